// Round 1
// baseline (231.993 us; speedup 1.0000x reference)
//
#include <hip/hip_runtime.h>

// out = (cum[j] + a[j]*(S - j/16)) / Y  with j = floor(16*S) clamped to [0,15]
//     = A[j]*S + B[j]
// A[j] = a[j]/Y, B[j] = (cum[j] - a[j]*j/16)/Y, a[j] = 0.5 + 4.5*sigmoid(u[j]),
// Y = sum(a)/16, cum[j] = sum_{i<j} a[i]/16.
//
// Memory-bound: 128 MiB in + 128 MiB out -> ~43 us floor at 6.3 TB/s.

#define MSEG 16

__global__ __launch_bounds__(256) void mapping_kernel(
    const float4* __restrict__ S4,
    const float*  __restrict__ u,
    float4*       __restrict__ out4,
    int n4)
{
    __shared__ float sA[MSEG];
    __shared__ float sB[MSEG];

    if (threadIdx.x == 0) {
        float a[MSEG];
        float Y = 0.0f;
        #pragma unroll
        for (int i = 0; i < MSEG; ++i) {
            float sig = 1.0f / (1.0f + expf(-u[i]));
            a[i] = 0.5f + 4.5f * sig;
            Y += a[i];
        }
        Y *= (1.0f / 16.0f);
        float invY = 1.0f / Y;
        float c = 0.0f;  // cum[j]
        #pragma unroll
        for (int i = 0; i < MSEG; ++i) {
            sA[i] = a[i] * invY;
            sB[i] = (c - a[i] * ((float)i * (1.0f / 16.0f))) * invY;
            c += a[i] * (1.0f / 16.0f);
        }
    }
    __syncthreads();

    int idx    = blockIdx.x * blockDim.x + threadIdx.x;
    int stride = gridDim.x * blockDim.x;

    for (int i = idx; i < n4; i += stride) {
        float4 s = S4[i];
        float4 r;
        int jx = min(max((int)(s.x * 16.0f), 0), 15);
        int jy = min(max((int)(s.y * 16.0f), 0), 15);
        int jz = min(max((int)(s.z * 16.0f), 0), 15);
        int jw = min(max((int)(s.w * 16.0f), 0), 15);
        r.x = fmaf(s.x, sA[jx], sB[jx]);
        r.y = fmaf(s.y, sA[jy], sB[jy]);
        r.z = fmaf(s.z, sA[jz], sB[jz]);
        r.w = fmaf(s.w, sA[jw], sB[jw]);
        out4[i] = r;
    }
}

extern "C" void kernel_launch(void* const* d_in, const int* in_sizes, int n_in,
                              void* d_out, int out_size, void* d_ws, size_t ws_size,
                              hipStream_t stream)
{
    const float4* S4 = (const float4*)d_in[0];   // [32,1024,1024] fp32
    const float*  u  = (const float*)d_in[1];    // [16] fp32
    // d_in[2] is M == 16, hardcoded.

    float4* out4 = (float4*)d_out;
    int n4 = out_size / 4;                       // 8,388,608 float4s

    const int block = 256;
    const int grid  = 8192;                      // grid-stride, 4 vec4/thread
    mapping_kernel<<<grid, block, 0, stream>>>(S4, u, out4, n4);
}

// Round 3
// 225.496 us; speedup vs baseline: 1.0288x; 1.0288x over previous
//
#include <hip/hip_runtime.h>

// out = A[j]*S + B[j],  j = floor(16*S) clamped to [0,15]
// A[j] = a[j]/Y, B[j] = (cum[j] - a[j]*j/16)/Y
// a[j] = 0.5 + 4.5*sigmoid(u[j]), Y = sum(a)/16, cum[j] = prefix(a)/16.
//
// Pure streaming op: 128 MiB in + 128 MiB out. Fill kernels on this box hit
// 6.6 TB/s -> target ~42-48 us for the dispatch itself.
// Static schedule: 4 independent float4 loads in flight per thread,
// non-temporal load+store (data never re-read; keep L2 clean).
// Note: nontemporal builtins need native vector types, not HIP_vector_type.

typedef float vf4 __attribute__((ext_vector_type(4)));

#define MSEG 16
#define VPT  4          // float4s per thread
#define BLK  256

__global__ __launch_bounds__(BLK) void mapping_kernel(
    const vf4* __restrict__ S4,
    const float* __restrict__ u,
    vf4* __restrict__ out4,
    int n4)
{
    __shared__ float sA[MSEG];
    __shared__ float sB[MSEG];

    if (threadIdx.x == 0) {
        float a[MSEG];
        float Y = 0.0f;
        #pragma unroll
        for (int i = 0; i < MSEG; ++i) {
            float sig = 1.0f / (1.0f + expf(-u[i]));
            a[i] = 0.5f + 4.5f * sig;
            Y += a[i];
        }
        Y *= (1.0f / 16.0f);
        float invY = 1.0f / Y;
        float c = 0.0f;  // cum[j]
        #pragma unroll
        for (int i = 0; i < MSEG; ++i) {
            sA[i] = a[i] * invY;
            sB[i] = (c - a[i] * ((float)i * (1.0f / 16.0f))) * invY;
            c += a[i] * (1.0f / 16.0f);
        }
    }
    __syncthreads();

    // Block covers BLK*VPT consecutive float4s; thread's k-th f4 is
    // block_base + k*BLK + tid -> every load/store wave-coalesced.
    const int base = blockIdx.x * (BLK * VPT) + threadIdx.x;

    vf4 v[VPT];
    #pragma unroll
    for (int k = 0; k < VPT; ++k) {
        const int i = base + k * BLK;
        if (i < n4) v[k] = __builtin_nontemporal_load(&S4[i]);
    }

    #pragma unroll
    for (int k = 0; k < VPT; ++k) {
        const int i = base + k * BLK;
        if (i < n4) {
            const vf4 s = v[k];
            vf4 r;
            const int jx = min(max((int)(s.x * 16.0f), 0), 15);
            const int jy = min(max((int)(s.y * 16.0f), 0), 15);
            const int jz = min(max((int)(s.z * 16.0f), 0), 15);
            const int jw = min(max((int)(s.w * 16.0f), 0), 15);
            r.x = fmaf(s.x, sA[jx], sB[jx]);
            r.y = fmaf(s.y, sA[jy], sB[jy]);
            r.z = fmaf(s.z, sA[jz], sB[jz]);
            r.w = fmaf(s.w, sA[jw], sB[jw]);
            __builtin_nontemporal_store(r, &out4[i]);
        }
    }
}

extern "C" void kernel_launch(void* const* d_in, const int* in_sizes, int n_in,
                              void* d_out, int out_size, void* d_ws, size_t ws_size,
                              hipStream_t stream)
{
    const vf4*  S4 = (const vf4*)d_in[0];        // [32,1024,1024] fp32
    const float* u = (const float*)d_in[1];      // [16] fp32
    // d_in[2] is M == 16, hardcoded.

    vf4* out4 = (vf4*)d_out;
    const int n4 = out_size / 4;                 // 8,388,608 float4s

    const int grid = (n4 + BLK * VPT - 1) / (BLK * VPT);  // 8192
    mapping_kernel<<<grid, BLK, 0, stream>>>(S4, u, out4, n4);
}

// Round 4
// 222.607 us; speedup vs baseline: 1.0422x; 1.0130x over previous
//
#include <hip/hip_runtime.h>

// out = A[j]*S + B[j],  j = floor(16*S) clamped to [0,15]
// A[j] = a[j]/Y, B[j] = (cum[j] - a[j]*j/16)/Y
// a[j] = 0.5 + 4.5*sigmoid(u[j]), Y = sum(a)/16, cum[j] = exclusive prefix(a)/16.
//
// Pure streaming op: 128 MiB in + 128 MiB out -> ~40 us floor at 6.7 TB/s
// (fill-kernel ceiling observed on this box).
// This round: lane-parallel table setup (shfl prefix-sum, no serial thread-0
// loop blocking the whole block) + VPT=8 (8 independent dwordx4 in flight)
// + branch-free fast path (n4 divides exactly; tail path kept but untaken).

typedef float vf4 __attribute__((ext_vector_type(4)));

#define MSEG 16
#define VPT  8          // float4s per thread
#define BLK  256

__global__ __launch_bounds__(BLK) void mapping_kernel(
    const vf4* __restrict__ S4,
    const float* __restrict__ u,
    vf4* __restrict__ out4,
    int n4)
{
    __shared__ float sA[MSEG];
    __shared__ float sB[MSEG];

    const int tid = threadIdx.x;

    // Lane-parallel table build in wave 0: 16 lanes compute a[i] at once,
    // log-step shfl prefix sum, write LDS. ~150 cyc + one load latency.
    if (tid < 64) {
        float a = 0.0f;
        if (tid < MSEG) {
            float sig = 1.0f / (1.0f + expf(-u[tid]));
            a = 0.5f + 4.5f * sig;
        }
        float p = a;  // inclusive prefix over lanes 0..15
        #pragma unroll
        for (int off = 1; off < MSEG; off <<= 1) {
            float t = __shfl_up(p, off, 64);
            if (tid >= off) p += t;
        }
        float total = __shfl(p, MSEG - 1, 64);  // sum of a[0..15]
        if (tid < MSEG) {
            float invY = 16.0f / total;               // Y = total/16
            float cum  = (p - a) * (1.0f / 16.0f);    // exclusive prefix /16
            sA[tid] = a * invY;
            sB[tid] = (cum - a * ((float)tid * (1.0f / 16.0f))) * invY;
        }
    }
    __syncthreads();

    // Block covers BLK*VPT consecutive float4s; thread's k-th f4 at
    // base + k*BLK -> every load/store wave-coalesced.
    const int base = blockIdx.x * (BLK * VPT) + tid;

    if (base + (VPT - 1) * BLK < n4) {
        // Fast path: no per-element bounds checks (exact cover).
        vf4 v[VPT];
        #pragma unroll
        for (int k = 0; k < VPT; ++k)
            v[k] = __builtin_nontemporal_load(&S4[base + k * BLK]);

        #pragma unroll
        for (int k = 0; k < VPT; ++k) {
            const vf4 s = v[k];
            vf4 r;
            const int jx = min(max((int)(s.x * 16.0f), 0), 15);
            const int jy = min(max((int)(s.y * 16.0f), 0), 15);
            const int jz = min(max((int)(s.z * 16.0f), 0), 15);
            const int jw = min(max((int)(s.w * 16.0f), 0), 15);
            r.x = fmaf(s.x, sA[jx], sB[jx]);
            r.y = fmaf(s.y, sA[jy], sB[jy]);
            r.z = fmaf(s.z, sA[jz], sB[jz]);
            r.w = fmaf(s.w, sA[jw], sB[jw]);
            __builtin_nontemporal_store(r, &out4[base + k * BLK]);
        }
    } else {
        // Tail path (never taken for 32x1024x1024, kept for generality).
        #pragma unroll
        for (int k = 0; k < VPT; ++k) {
            const int i = base + k * BLK;
            if (i < n4) {
                const vf4 s = __builtin_nontemporal_load(&S4[i]);
                vf4 r;
                const int jx = min(max((int)(s.x * 16.0f), 0), 15);
                const int jy = min(max((int)(s.y * 16.0f), 0), 15);
                const int jz = min(max((int)(s.z * 16.0f), 0), 15);
                const int jw = min(max((int)(s.w * 16.0f), 0), 15);
                r.x = fmaf(s.x, sA[jx], sB[jx]);
                r.y = fmaf(s.y, sA[jy], sB[jy]);
                r.z = fmaf(s.z, sA[jz], sB[jz]);
                r.w = fmaf(s.w, sA[jw], sB[jw]);
                __builtin_nontemporal_store(r, &out4[i]);
            }
        }
    }
}

extern "C" void kernel_launch(void* const* d_in, const int* in_sizes, int n_in,
                              void* d_out, int out_size, void* d_ws, size_t ws_size,
                              hipStream_t stream)
{
    const vf4*  S4 = (const vf4*)d_in[0];        // [32,1024,1024] fp32
    const float* u = (const float*)d_in[1];      // [16] fp32
    // d_in[2] is M == 16, hardcoded.

    vf4* out4 = (vf4*)d_out;
    const int n4 = out_size / 4;                 // 8,388,608 float4s

    const int grid = (n4 + BLK * VPT - 1) / (BLK * VPT);  // 4096
    mapping_kernel<<<grid, BLK, 0, stream>>>(S4, u, out4, n4);
}